// Round 6
// baseline (229.626 us; speedup 1.0000x reference)
//
#include <hip/hip_runtime.h>

typedef __bf16 bf16x8 __attribute__((ext_vector_type(8)));
typedef __bf16 bf16x4 __attribute__((ext_vector_type(4)));
typedef float  f32x4  __attribute__((ext_vector_type(4)));

#define B_ 4
#define T_ 2048
#define H_ 8
#define D_ 64
#define E_ 512

// q scale: D^-0.5 * log2(e)  (softmax computed in exp2 domain)
#define QSCALE 0.18033688011112042f

// async global->LDS, 16B per lane. LDS dest is wave-uniform base + lane*16.
__device__ __forceinline__ void async_ld16(const __bf16* g, __bf16* lds) {
  __builtin_amdgcn_global_load_lds((const __attribute__((address_space(1))) void*)g,
                                   (__attribute__((address_space(3))) void*)lds,
                                   16, 0, 0);
}

// converts x, W_qkv (row-permuted to [which][h][d] order), W_0
__global__ void cvt_all(const float* __restrict__ x, const float* __restrict__ wq,
                        const float* __restrict__ w0, __bf16* __restrict__ xb,
                        __bf16* __restrict__ wqb, __bf16* __restrict__ w0b) {
  long i = (long)(blockIdx.x * 256 + threadIdx.x) * 8;
  const float* src; __bf16* dst; long roff, woff;
  if (i < 4194304L)      { src = x;  dst = xb;  roff = i; woff = i; }
  else if (i < 4980736L) {
    src = wq; dst = wqb; roff = i - 4194304L;
    // src row r = h*192 + d*3 + which  ->  dst row = which*512 + h*64 + d
    const int r = (int)(roff >> 9), c = (int)(roff & 511);
    const int h = r / 192, rem = r - h * 192;
    const int d = rem / 3, which = rem - d * 3;
    woff = (long)(which * 512 + h * 64 + d) * 512 + c;
  }
  else                   { src = w0; dst = w0b; roff = i - 4980736L; woff = roff; }
  float4 a = *(const float4*)(src + roff);
  float4 b = *(const float4*)(src + roff + 4);
  bf16x8 o;
  o[0] = (__bf16)a.x; o[1] = (__bf16)a.y; o[2] = (__bf16)a.z; o[3] = (__bf16)a.w;
  o[4] = (__bf16)b.x; o[5] = (__bf16)b.y; o[6] = (__bf16)b.z; o[7] = (__bf16)b.w;
  *(bf16x8*)(dst + woff) = o;
}

// C = A(MxK) * B(NxK)^T, K=512, 128x128 tile, 4 waves, 16x16x32 bf16 MFMA.
// Double-buffered staging, one barrier per K-step.
// MODE 0: qkv epilogue (W pre-permuted -> which = n0>>9 block-uniform).
// MODE 1: plain fp32 store, row-major MxN.
template<int MODE, int N>
__global__ __launch_bounds__(256, 2)
void gemm_bt(const __bf16* __restrict__ A, const __bf16* __restrict__ Bm,
             __bf16* __restrict__ o0, __bf16* __restrict__ o1, __bf16* __restrict__ o2,
             float* __restrict__ of) {
  constexpr int K = 512;
  __shared__ __bf16 As[2][128 * 64];
  __shared__ __bf16 Bs[2][128 * 64];
  const int tid  = threadIdx.x;
  const int wave = tid >> 6, lane = tid & 63;
  const int l15 = lane & 15, l16 = lane >> 4;
  const int m0 = blockIdx.y * 128, n0 = blockIdx.x * 128;
  const int waveM = wave >> 1, waveN = wave & 1;
  const int srow = lane >> 3;
  const int sch  = (lane & 7) ^ srow;

  f32x4 acc[4][4] = {};

  const __bf16* ag = A  + (size_t)(m0 + wave * 8 + srow) * K + sch * 8;
  const __bf16* bg = Bm + (size_t)(n0 + wave * 8 + srow) * K + sch * 8;

  auto stage = [&](int buf, int k0) {
#pragma unroll
    for (int it = 0; it < 4; ++it) {
      async_ld16(ag + (size_t)it * 32 * K + k0, &As[buf][(it * 32 + wave * 8) * 64]);
      async_ld16(bg + (size_t)it * 32 * K + k0, &Bs[buf][(it * 32 + wave * 8) * 64]);
    }
  };

  stage(0, 0);
#pragma unroll 2
  for (int kt = 0; kt < 8; ++kt) {
    __builtin_amdgcn_s_waitcnt(0);
    __syncthreads();
    if (kt < 7) stage((kt + 1) & 1, (kt + 1) * 64);
    const __bf16* Ac = As[kt & 1];
    const __bf16* Bc = Bs[kt & 1];
#pragma unroll
    for (int ks = 0; ks < 2; ++ks) {
      bf16x8 af[4], bf[4];
      const int cb = ks * 4 + l16;
#pragma unroll
      for (int i = 0; i < 4; ++i) {
        const int rA = waveM * 64 + i * 16 + l15;
        const int rB = waveN * 64 + i * 16 + l15;
        af[i] = *(const bf16x8*)&Ac[rA * 64 + ((cb ^ (rA & 7)) * 8)];
        bf[i] = *(const bf16x8*)&Bc[rB * 64 + ((cb ^ (rB & 7)) * 8)];
      }
#pragma unroll
      for (int mi = 0; mi < 4; ++mi)
#pragma unroll
        for (int ni = 0; ni < 4; ++ni)
          acc[mi][ni] = __builtin_amdgcn_mfma_f32_16x16x32_bf16(af[mi], bf[ni], acc[mi][ni], 0, 0, 0);
    }
  }

  if constexpr (MODE == 0) {
    const int which = n0 >> 9;          // block-uniform after W permutation
    const int b = m0 >> 11;
#pragma unroll
    for (int mi = 0; mi < 4; ++mi) {
#pragma unroll
      for (int ni = 0; ni < 4; ++ni) {
        const int n = n0 + waveN * 64 + ni * 16 + l15;
        const int d = n & 63, h = (n >> 6) & 7;
        const int t = (m0 & (T_ - 1)) + waveM * 64 + mi * 16 + l16 * 4;
        const size_t bh = (size_t)(b * H_ + h);
        if (which == 0) {
          bf16x4 pv;
#pragma unroll
          for (int r = 0; r < 4; ++r) pv[r] = (__bf16)(acc[mi][ni][r] * QSCALE);
          *(bf16x4*)&o0[(bh * D_ + d) * T_ + t] = pv;            // q [B,H,D,T]
        } else if (which == 1) {
#pragma unroll
          for (int r = 0; r < 4; ++r)
            o1[(bh * T_ + t + r) * D_ + d] = (__bf16)acc[mi][ni][r];  // k [B,H,T,D]
        } else {
          bf16x4 pv;
#pragma unroll
          for (int r = 0; r < 4; ++r) pv[r] = (__bf16)acc[mi][ni][r];
          *(bf16x4*)&o2[(bh * D_ + d) * T_ + t] = pv;            // v [B,H,D,T]
        }
      }
    }
  } else {
#pragma unroll
    for (int mi = 0; mi < 4; ++mi)
#pragma unroll
      for (int ni = 0; ni < 4; ++ni)
#pragma unroll
        for (int r = 0; r < 4; ++r) {
          const int m = m0 + waveM * 64 + mi * 16 + l16 * 4 + r;
          const int n = n0 + waveN * 64 + ni * 16 + l15;
          of[(size_t)m * N + n] = acc[mi][ni][r];
        }
  }
}

// Flash attention, barrier-free. Each wave independently owns 32 q-cols x full
// T: K/V fragments loaded straight from global to registers (4 waves of a
// block read identical addresses -> L1 broadcast; K/V per bh is L2-resident).
// LDS only for the wave-private P round-trip (parity double-buffered).
// Max-free exp2-domain softmax; row-sum l via ones-MFMA (rows match oacc).
__global__ __launch_bounds__(256, 2)
void attn_kernel(const __bf16* __restrict__ Q, const __bf16* __restrict__ Kk,
                 const __bf16* __restrict__ Vt, __bf16* __restrict__ Out) {
  __shared__ __align__(16) __bf16 Ps[4 * 2 * 1280];  // per wave x parity: [32 q][40]

  const int tid = threadIdx.x, wave = tid >> 6, lane = tid & 63;
  const int l15 = lane & 15, l16 = lane >> 4;
  const int bh  = blockIdx.y;
  const int q0  = blockIdx.x * 128 + wave * 32;      // wave's q-range
  const __bf16* qptr = Q  + (size_t)bh * D_ * T_;    // [D][T], pre-scaled
  const __bf16* kptr = Kk + (size_t)bh * T_ * D_;    // [T][D]
  const __bf16* vptr = Vt + (size_t)bh * D_ * T_;    // [D][T]

  __bf16* Pw = Ps + wave * 2560;

  // Q fragments: B-op for S^T: B[k=d=l16*8+j][n=q=l15]; one-time scalar loads.
  bf16x8 qf[2][2];
#pragma unroll
  for (int ni = 0; ni < 2; ++ni)
#pragma unroll
    for (int ks = 0; ks < 2; ++ks)
#pragma unroll
      for (int j = 0; j < 8; ++j)
        qf[ni][ks][j] = qptr[(size_t)(ks * 32 + l16 * 8 + j) * T_ + q0 + ni * 16 + l15];

  bf16x8 ones;
#pragma unroll
  for (int j = 0; j < 8; ++j) ones[j] = (__bf16)1.0f;

  f32x4 oacc[2][4] = {};
  f32x4 lacc[2] = {};

  // K frag: A[m=t=l15 (+16mt)][k=d=l16*8+j (+32ks)]  -> b128 per lane
  // V frag: B[k=t=l16*8+j][n=d=l15 (+16nd)]          -> b128 per lane
  auto ldK = [&](bf16x8 (&kf)[2][2], int t0) {
#pragma unroll
    for (int mt = 0; mt < 2; ++mt)
#pragma unroll
      for (int ks = 0; ks < 2; ++ks)
        kf[mt][ks] = *(const bf16x8*)(kptr + (size_t)(t0 + mt * 16 + l15) * D_ +
                                      ks * 32 + l16 * 8);
  };
  auto ldV = [&](bf16x8 (&vf)[4], int t0) {
#pragma unroll
    for (int nd = 0; nd < 4; ++nd)
      vf[nd] = *(const bf16x8*)(vptr + (size_t)(nd * 16 + l15) * T_ + t0 + l16 * 8);
  };

  bf16x8 kf[2][2][2], vf[2][4];
  ldK(kf[0], 0);  ldV(vf[0], 0);
  ldK(kf[1], 32); ldV(vf[1], 32);

#pragma unroll 2
  for (int kt = 0; kt < 64; ++kt) {
    const int pp = kt & 1;
    const int tnext = ((kt + 2) & 63) * 32;   // wrap keeps address in-bounds; unused at tail
    __bf16* Pb = Pw + pp * 1280;

    // S^T[t32][q32] in log2 domain
    f32x4 sacc[2][2] = {};
#pragma unroll
    for (int ks = 0; ks < 2; ++ks)
#pragma unroll
      for (int mt = 0; mt < 2; ++mt)
#pragma unroll
        for (int ni = 0; ni < 2; ++ni)
          sacc[mt][ni] = __builtin_amdgcn_mfma_f32_16x16x32_bf16(kf[pp][mt][ks], qf[ni][ks],
                                                                 sacc[mt][ni], 0, 0, 0);
    ldK(kf[pp], tnext);   // prefetch K for kt+2 (regs just consumed)

    // P = exp2(S) -> Ps[q][t] (stride 40)
#pragma unroll
    for (int ni = 0; ni < 2; ++ni)
#pragma unroll
      for (int mt = 0; mt < 2; ++mt) {
        bf16x4 pv;
#pragma unroll
        for (int r = 0; r < 4; ++r) pv[r] = (__bf16)__builtin_amdgcn_exp2f(sacc[mt][ni][r]);
        *(bf16x4*)&Pb[(ni * 16 + l15) * 40 + mt * 16 + l16 * 4] = pv;
      }

    // A-frags of P, then O += P*V, l += P*1
    bf16x8 pf[2];
#pragma unroll
    for (int mq = 0; mq < 2; ++mq)
      pf[mq] = *(const bf16x8*)&Pb[(mq * 16 + l15) * 40 + l16 * 8];
#pragma unroll
    for (int mq = 0; mq < 2; ++mq) {
#pragma unroll
      for (int nd = 0; nd < 4; ++nd)
        oacc[mq][nd] = __builtin_amdgcn_mfma_f32_16x16x32_bf16(pf[mq], vf[pp][nd],
                                                               oacc[mq][nd], 0, 0, 0);
      lacc[mq] = __builtin_amdgcn_mfma_f32_16x16x32_bf16(pf[mq], ones, lacc[mq], 0, 0, 0);
    }
    ldV(vf[pp], tnext);   // prefetch V for kt+2
  }

  // epilogue: O /= l -> Out[B,T,H*D] bf16 (lane cols consecutive -> coalesced)
  const int b = bh >> 3, hcol = (bh & 7) * D_;
#pragma unroll
  for (int mq = 0; mq < 2; ++mq) {
    f32x4 linv;
#pragma unroll
    for (int r = 0; r < 4; ++r) linv[r] = __builtin_amdgcn_rcpf(lacc[mq][r]);
#pragma unroll
    for (int nd = 0; nd < 4; ++nd)
#pragma unroll
      for (int r = 0; r < 4; ++r) {
        const int trow = q0 + mq * 16 + l16 * 4 + r;
        Out[((size_t)b * T_ + trow) * E_ + hcol + nd * 16 + l15] =
            (__bf16)(oacc[mq][nd][r] * linv[r]);
      }
  }
}

extern "C" void kernel_launch(void* const* d_in, const int* in_sizes, int n_in,
                              void* d_out, int out_size, void* d_ws, size_t ws_size,
                              hipStream_t stream) {
  const float* x    = (const float*)d_in[0];
  const float* Wqkv = (const float*)d_in[1];
  const float* W0   = (const float*)d_in[2];
  float* out = (float*)d_out;

  char* ws = (char*)d_ws;
  __bf16* xb  = (__bf16*)ws;                                    // 8192*512 bf16
  __bf16* wqb = (__bf16*)(ws + 8388608);                        // 1536*512 (permuted)
  __bf16* w0b = (__bf16*)(ws + 8388608 + 1572864);              // 512*512
  __bf16* q   = (__bf16*)(ws + 8388608 + 1572864 + 524288);     // [B,H,D,T]
  __bf16* k   = q + 4194304;                                    // [B,H,T,D]
  __bf16* v   = k + 4194304;                                    // [B,H,D,T]
  __bf16* ao  = xb;  // reuse: xb consumed by QKV GEMM before attn writes ao

  cvt_all<<<2560, 256, 0, stream>>>(x, Wqkv, W0, xb, wqb, w0b);
  gemm_bt<0, 3 * H_ * D_><<<dim3(12, 64), 256, 0, stream>>>(xb, wqb, q, k, v, nullptr);
  attn_kernel<<<dim3(16, 32), 256, 0, stream>>>(q, k, v, ao);
  gemm_bt<1, E_><<<dim3(4, 64), 256, 0, stream>>>(ao, w0b, nullptr, nullptr, nullptr, out);
}

// Round 7
// 165.858 us; speedup vs baseline: 1.3845x; 1.3845x over previous
//
#include <hip/hip_runtime.h>

typedef __bf16 bf16x8 __attribute__((ext_vector_type(8)));
typedef __bf16 bf16x4 __attribute__((ext_vector_type(4)));
typedef float  f32x4  __attribute__((ext_vector_type(4)));

#define B_ 4
#define T_ 2048
#define H_ 8
#define D_ 64
#define E_ 512

// q scale: D^-0.5 * log2(e)  (softmax computed in exp2 domain)
#define QSCALE 0.18033688011112042f

// async global->LDS, 16B per lane. LDS dest is wave-uniform base + lane*16.
__device__ __forceinline__ void async_ld16(const __bf16* g, __bf16* lds) {
  __builtin_amdgcn_global_load_lds((const __attribute__((address_space(1))) void*)g,
                                   (__attribute__((address_space(3))) void*)lds,
                                   16, 0, 0);
}

// converts x, W_qkv (row-permuted to [which][h][d] order), W_0
__global__ void cvt_all(const float* __restrict__ x, const float* __restrict__ wq,
                        const float* __restrict__ w0, __bf16* __restrict__ xb,
                        __bf16* __restrict__ wqb, __bf16* __restrict__ w0b) {
  long i = (long)(blockIdx.x * 256 + threadIdx.x) * 8;
  const float* src; __bf16* dst; long roff, woff;
  if (i < 4194304L)      { src = x;  dst = xb;  roff = i; woff = i; }
  else if (i < 4980736L) {
    src = wq; dst = wqb; roff = i - 4194304L;
    // src row r = h*192 + d*3 + which  ->  dst row = which*512 + h*64 + d
    const int r = (int)(roff >> 9), c = (int)(roff & 511);
    const int h = r / 192, rem = r - h * 192;
    const int d = rem / 3, which = rem - d * 3;
    woff = (long)(which * 512 + h * 64 + d) * 512 + c;
  }
  else                   { src = w0; dst = w0b; roff = i - 4980736L; woff = roff; }
  float4 a = *(const float4*)(src + roff);
  float4 b = *(const float4*)(src + roff + 4);
  bf16x8 o;
  o[0] = (__bf16)a.x; o[1] = (__bf16)a.y; o[2] = (__bf16)a.z; o[3] = (__bf16)a.w;
  o[4] = (__bf16)b.x; o[5] = (__bf16)b.y; o[6] = (__bf16)b.z; o[7] = (__bf16)b.w;
  *(bf16x8*)(dst + woff) = o;
}

// C = A(MxK) * B(NxK)^T, K=512, TMx128 tile, 4 waves, 16x16x32 bf16 MFMA.
// Double-buffered staging, one barrier per K-step.
// MODE 0 (TM=128): qkv epilogue (W pre-permuted -> which = n0>>9 block-uniform).
// MODE 1: plain fp32 store, row-major MxN.
template<int MODE, int N, int TM>
__global__ __launch_bounds__(256, 2)
void gemm_bt(const __bf16* __restrict__ A, const __bf16* __restrict__ Bm,
             __bf16* __restrict__ o0, __bf16* __restrict__ o1, __bf16* __restrict__ o2,
             float* __restrict__ of) {
  constexpr int K = 512;
  constexpr int MI = TM / 32;                 // acc tiles in m per wave
  __shared__ __bf16 As[2][TM * 64];
  __shared__ __bf16 Bs[2][128 * 64];
  const int tid  = threadIdx.x;
  const int wave = tid >> 6, lane = tid & 63;
  const int l15 = lane & 15, l16 = lane >> 4;
  const int m0 = blockIdx.y * TM, n0 = blockIdx.x * 128;
  const int waveM = wave >> 1, waveN = wave & 1;
  const int srow = lane >> 3;
  const int sch  = (lane & 7) ^ srow;

  f32x4 acc[MI][4] = {};

  const __bf16* ag = A  + (size_t)(m0 + wave * 8 + srow) * K + sch * 8;
  const __bf16* bg = Bm + (size_t)(n0 + wave * 8 + srow) * K + sch * 8;

  auto stage = [&](int buf, int k0) {
#pragma unroll
    for (int it = 0; it < TM / 32; ++it)
      async_ld16(ag + (size_t)it * 32 * K + k0, &As[buf][(it * 32 + wave * 8) * 64]);
#pragma unroll
    for (int it = 0; it < 4; ++it)
      async_ld16(bg + (size_t)it * 32 * K + k0, &Bs[buf][(it * 32 + wave * 8) * 64]);
  };

  stage(0, 0);
#pragma unroll 2
  for (int kt = 0; kt < 8; ++kt) {
    __builtin_amdgcn_s_waitcnt(0);
    __syncthreads();
    if (kt < 7) stage((kt + 1) & 1, (kt + 1) * 64);
    const __bf16* Ac = As[kt & 1];
    const __bf16* Bc = Bs[kt & 1];
#pragma unroll
    for (int ks = 0; ks < 2; ++ks) {
      bf16x8 af[MI], bf[4];
      const int cb = ks * 4 + l16;
#pragma unroll
      for (int i = 0; i < MI; ++i) {
        const int rA = waveM * (TM / 2) + i * 16 + l15;
        af[i] = *(const bf16x8*)&Ac[rA * 64 + ((cb ^ (rA & 7)) * 8)];
      }
#pragma unroll
      for (int i = 0; i < 4; ++i) {
        const int rB = waveN * 64 + i * 16 + l15;
        bf[i] = *(const bf16x8*)&Bs[kt & 1][rB * 64 + ((cb ^ (rB & 7)) * 8)];
      }
#pragma unroll
      for (int mi = 0; mi < MI; ++mi)
#pragma unroll
        for (int ni = 0; ni < 4; ++ni)
          acc[mi][ni] = __builtin_amdgcn_mfma_f32_16x16x32_bf16(af[mi], bf[ni], acc[mi][ni], 0, 0, 0);
    }
  }

  if constexpr (MODE == 0) {
    const int which = n0 >> 9;          // block-uniform after W permutation
    const int b = m0 >> 11;
#pragma unroll
    for (int mi = 0; mi < MI; ++mi) {
#pragma unroll
      for (int ni = 0; ni < 4; ++ni) {
        const int n = n0 + waveN * 64 + ni * 16 + l15;
        const int d = n & 63, h = (n >> 6) & 7;
        const int t = (m0 & (T_ - 1)) + waveM * (TM / 2) + mi * 16 + l16 * 4;
        const size_t bh = (size_t)(b * H_ + h);
        if (which == 0) {
          bf16x4 pv;
#pragma unroll
          for (int r = 0; r < 4; ++r) pv[r] = (__bf16)(acc[mi][ni][r] * QSCALE);
          *(bf16x4*)&o0[(bh * D_ + d) * T_ + t] = pv;            // q [B,H,D,T]
        } else if (which == 1) {
#pragma unroll
          for (int r = 0; r < 4; ++r)
            o1[(bh * T_ + t + r) * D_ + d] = (__bf16)acc[mi][ni][r];  // k [B,H,T,D]
        } else {
          bf16x4 pv;
#pragma unroll
          for (int r = 0; r < 4; ++r) pv[r] = (__bf16)acc[mi][ni][r];
          *(bf16x4*)&o2[(bh * D_ + d) * T_ + t] = pv;            // v [B,H,D,T]
        }
      }
    }
  } else {
#pragma unroll
    for (int mi = 0; mi < MI; ++mi)
#pragma unroll
      for (int ni = 0; ni < 4; ++ni)
#pragma unroll
        for (int r = 0; r < 4; ++r) {
          const int m = m0 + waveM * (TM / 2) + mi * 16 + l16 * 4 + r;
          const int n = n0 + waveN * 64 + ni * 16 + l15;
          of[(size_t)m * N + n] = acc[mi][ni][r];
        }
  }
}

// Flash attention, max-free exp2-domain. q-tile 64 per block (grid 1024 ->
// ~3-4 independent blocks/CU: inter-block de-phasing fills MFMA/VALU/LDS
// pipes). Tk=64 double-buffered K/V staging, one barrier per kt.
// Waves 2x2 over (t-half 32, q-half 32); Ps wave-private.
__global__ __launch_bounds__(256, 3)
void attn_kernel(const __bf16* __restrict__ Q, const __bf16* __restrict__ Kk,
                 const __bf16* __restrict__ Vt, __bf16* __restrict__ Out) {
  __shared__ __align__(16) char smem[43008];
  // Ks[2]: 0, 8192 ([64 t][64 d] swizzled). Vts[2]: 16384, 24576 ([64 d][64 t]).
  // Ps: 32768, per-wave [32 q][40] bf16 (2560 B each).
  float* Osh = (float*)smem;               // overlay: [2 q2][32 q][... [d][q] f32
  float* Lsh = (float*)(smem + 20480);     // overlay: [2 q2][32 q] f32

  const int tid = threadIdx.x, wave = tid >> 6, lane = tid & 63;
  const int l15 = lane & 15, l16 = lane >> 4;
  const int tw = wave >> 1, q2 = wave & 1;
  const int bh  = blockIdx.y;
  const int t0q = blockIdx.x * 64;
  const __bf16* qptr = Q  + (size_t)bh * D_ * T_;   // [D][T], pre-scaled
  const __bf16* kptr = Kk + (size_t)bh * T_ * D_;   // [T][D]
  const __bf16* vptr = Vt + (size_t)bh * D_ * T_;   // [D][T]

  __bf16* Pw = (__bf16*)(smem + 32768) + wave * 1280;  // [32 q][40]

  // Q fragments (wave's 32 q-cols), from [d][t]: one-time scalar loads.
  bf16x8 qf[2][2];
#pragma unroll
  for (int ni = 0; ni < 2; ++ni)
#pragma unroll
    for (int ks = 0; ks < 2; ++ks)
#pragma unroll
      for (int j = 0; j < 8; ++j)
        qf[ni][ks][j] = qptr[(size_t)(ks * 32 + l16 * 8 + j) * T_ +
                             t0q + q2 * 32 + ni * 16 + l15];

  bf16x8 ones;
#pragma unroll
  for (int j = 0; j < 8; ++j) ones[j] = (__bf16)1.0f;

  f32x4 oacc[2][4] = {};
  f32x4 lacc[2] = {};

  const int srow = lane >> 3;
  const int sch  = (lane & 7) ^ srow;

  auto stage = [&](int buf, int t0k) {
    __bf16* Kd = (__bf16*)(smem + buf * 8192);
    __bf16* Vd = (__bf16*)(smem + 16384 + buf * 8192);
#pragma unroll
    for (int i = 0; i < 2; ++i) {
      const int row = i * 32 + wave * 8;
      async_ld16(kptr + (size_t)(t0k + row + srow) * D_ + sch * 8, Kd + row * 64);
      async_ld16(vptr + (size_t)(row + srow) * T_ + t0k + sch * 8, Vd + row * 64);
    }
  };

  stage(0, 0);
#pragma unroll 2
  for (int kt = 0; kt < 32; ++kt) {
    __builtin_amdgcn_s_waitcnt(0);
    __syncthreads();
    if (kt < 31) stage((kt + 1) & 1, (kt + 1) * 64);
    const __bf16* Ksc = (const __bf16*)(smem + (kt & 1) * 8192);
    const __bf16* Vtc = (const __bf16*)(smem + 16384 + (kt & 1) * 8192);

    // S^T[t'][q'] over wave's 32 t x 32 q (log2 domain via QSCALE)
    f32x4 sacc[2][2] = {};
#pragma unroll
    for (int ks = 0; ks < 2; ++ks) {
      bf16x8 kf[2];
      const int cb = ks * 4 + l16;
#pragma unroll
      for (int mi = 0; mi < 2; ++mi) {
        const int rt = tw * 32 + mi * 16 + l15;
        kf[mi] = *(const bf16x8*)&Ksc[rt * 64 + ((cb ^ (rt & 7)) * 8)];
      }
#pragma unroll
      for (int mi = 0; mi < 2; ++mi)
#pragma unroll
        for (int ni = 0; ni < 2; ++ni)
          sacc[mi][ni] = __builtin_amdgcn_mfma_f32_16x16x32_bf16(kf[mi], qf[ni][ks], sacc[mi][ni], 0, 0, 0);
    }

    // P = exp2(S) -> wave-private Ps [q'][t' stride 40]
#pragma unroll
    for (int ni = 0; ni < 2; ++ni)
#pragma unroll
      for (int mi = 0; mi < 2; ++mi) {
        bf16x4 pv;
#pragma unroll
        for (int r = 0; r < 4; ++r) pv[r] = (__bf16)__builtin_amdgcn_exp2f(sacc[mi][ni][r]);
        *(bf16x4*)&Pw[(ni * 16 + l15) * 40 + mi * 16 + l16 * 4] = pv;
      }

    // O += P*V over wave's 32 t ; l += P*1
    {
      bf16x8 pf[2], vf[4];
#pragma unroll
      for (int mq = 0; mq < 2; ++mq)
        pf[mq] = *(const bf16x8*)&Pw[(mq * 16 + l15) * 40 + l16 * 8];
#pragma unroll
      for (int nd = 0; nd < 4; ++nd) {
        const int rd = nd * 16 + l15;
        const int ct = tw * 4 + l16;
        vf[nd] = *(const bf16x8*)&Vtc[rd * 64 + ((ct ^ (rd & 7)) * 8)];
      }
#pragma unroll
      for (int mq = 0; mq < 2; ++mq) {
#pragma unroll
        for (int nd = 0; nd < 4; ++nd)
          oacc[mq][nd] = __builtin_amdgcn_mfma_f32_16x16x32_bf16(pf[mq], vf[nd], oacc[mq][nd], 0, 0, 0);
        lacc[mq] = __builtin_amdgcn_mfma_f32_16x16x32_bf16(pf[mq], ones, lacc[mq], 0, 0, 0);
      }
    }
  }

  // reduce O,l across t-halves; epilogue O/l -> [B,T,H*D] bf16
  __syncthreads();
  if (tw == 1) {
    float* Ow = Osh + q2 * 2304;            // [64 d][36] f32
#pragma unroll
    for (int mq = 0; mq < 2; ++mq)
#pragma unroll
      for (int nd = 0; nd < 4; ++nd)
        *(f32x4*)&Ow[(nd * 16 + l15) * 36 + mq * 16 + l16 * 4] = oacc[mq][nd];
    if (l15 == 0)
#pragma unroll
      for (int mq = 0; mq < 2; ++mq)
        *(f32x4*)&Lsh[q2 * 32 + mq * 16 + l16 * 4] = lacc[mq];
  }
  __syncthreads();
  if (tw == 0) {
    const int b = bh >> 3, hcol = (bh & 7) * D_;
    float* Ow = Osh + q2 * 2304;
#pragma unroll
    for (int mq = 0; mq < 2; ++mq) {
      const f32x4 lv = *(const f32x4*)&Lsh[q2 * 32 + mq * 16 + l16 * 4];
      f32x4 linv;
#pragma unroll
      for (int r = 0; r < 4; ++r) linv[r] = __builtin_amdgcn_rcpf(lacc[mq][r] + lv[r]);
#pragma unroll
      for (int nd = 0; nd < 4; ++nd) {
        const f32x4 op = *(const f32x4*)&Ow[(nd * 16 + l15) * 36 + mq * 16 + l16 * 4];
#pragma unroll
        for (int r = 0; r < 4; ++r) {
          const int trow = t0q + q2 * 32 + mq * 16 + l16 * 4 + r;
          Out[((size_t)b * T_ + trow) * E_ + hcol + nd * 16 + l15] =
              (__bf16)((oacc[mq][nd][r] + op[r]) * linv[r]);
        }
      }
    }
  }
}

extern "C" void kernel_launch(void* const* d_in, const int* in_sizes, int n_in,
                              void* d_out, int out_size, void* d_ws, size_t ws_size,
                              hipStream_t stream) {
  const float* x    = (const float*)d_in[0];
  const float* Wqkv = (const float*)d_in[1];
  const float* W0   = (const float*)d_in[2];
  float* out = (float*)d_out;

  char* ws = (char*)d_ws;
  __bf16* xb  = (__bf16*)ws;                                    // 8192*512 bf16
  __bf16* wqb = (__bf16*)(ws + 8388608);                        // 1536*512 (permuted)
  __bf16* w0b = (__bf16*)(ws + 8388608 + 1572864);              // 512*512
  __bf16* q   = (__bf16*)(ws + 8388608 + 1572864 + 524288);     // [B,H,D,T]
  __bf16* k   = q + 4194304;                                    // [B,H,T,D]
  __bf16* v   = k + 4194304;                                    // [B,H,D,T]
  __bf16* ao  = xb;  // reuse: xb consumed by QKV GEMM before attn writes ao

  cvt_all<<<2560, 256, 0, stream>>>(x, Wqkv, W0, xb, wqb, w0b);
  gemm_bt<0, 3 * H_ * D_, 128><<<dim3(12, 64), 256, 0, stream>>>(xb, wqb, q, k, v, nullptr);
  attn_kernel<<<dim3(32, 32), 256, 0, stream>>>(q, k, v, ao);
  gemm_bt<1, E_, 64><<<dim3(4, 128), 256, 0, stream>>>(ao, w0b, nullptr, nullptr, nullptr, out);
}